// Round 2
// baseline (663.191 us; speedup 1.0000x reference)
//
#include <hip/hip_runtime.h>

#define B_SZ 256
#define D_SZ 1024
#define F_SZ 4096
#define K_SZ 8
#define S_SZ 8
#define NW   (2 * K_SZ * F_SZ)   /* 65536 combined gate|up weight rows */
#define SD   (S_SZ * D_SZ)       /* 8192 */

typedef __attribute__((ext_vector_type(4))) float f32x4v;
typedef __attribute__((ext_vector_type(8))) short s16x8v;

/* LDS XOR swizzle (T2): elem col ^= (row&7)<<3  (rows are 64 elems = 128 B) */
#define SWZ(row, col) ((col) ^ (((row) & 7) << 3))

static __device__ __forceinline__ unsigned short f2bf(float f) {
    union { float f; unsigned u; } v; v.f = f;
    unsigned u = v.u;
    unsigned r = u + 0x7FFFu + ((u >> 16) & 1u);   /* RNE */
    return (unsigned short)(r >> 16);
}
static __device__ __forceinline__ float bf2f(unsigned short h) {
    union { unsigned u; float f; } v; v.u = ((unsigned)h) << 16;
    return v.f;
}

/* ------------------------------------------------------------------ K0:
   convert x (B*D fp32) -> bf16, row-major [256][1024] */
__global__ __launch_bounds__(256) void k_cvt_x(const float* __restrict__ x,
                                               unsigned short* __restrict__ xs) {
    int g = blockIdx.x * 256 + threadIdx.x;
    float4 v = reinterpret_cast<const float4*>(x)[g];
    ushort4 h;
    h.x = f2bf(v.x); h.y = f2bf(v.y); h.z = f2bf(v.z); h.w = f2bf(v.w);
    reinterpret_cast<ushort4*>(xs)[g] = h;
}

/* ------------------------------------------------------------------ K1:
   bank[256][65536] (bf16) = xs[256][1024] @ W^T, W = [gate_w; up_w] fp32.
   BM=256, BN=64, BK=64. 512 thr = 8 waves (4M x 2N), wave tile 64x32.
   LDS 80 KB -> 2 blocks/CU; launch_bounds(512,4) caps VGPR at 128 so the
   2nd block actually fits. Grid 1024 = 4 blocks/CU scheduled -> independent
   barrier groups overlap each other's vmcnt drains (m114). Weights are
   read exactly once (BM = full M). */
__global__ __launch_bounds__(512, 4)
void k_bank_gemm(const unsigned short* __restrict__ xs,
                 const float* __restrict__ gw,
                 const float* __restrict__ uw,
                 unsigned short* __restrict__ bank) {
    __shared__ unsigned short As[2][256 * 64];   /* 2 x 32 KB */
    __shared__ unsigned short Bs[2][64 * 64];    /* 2 x  8 KB */

    const int tid  = threadIdx.x;
    const int lane = tid & 63;
    const int wid  = tid >> 6;
    const int wm   = wid >> 1;          /* 0..3 */
    const int wn   = wid & 1;           /* 0..1 */
    const int n0   = blockIdx.x * 64;

    f32x4v acc[4][2];
    #pragma unroll
    for (int i = 0; i < 4; i++)
        #pragma unroll
        for (int j = 0; j < 2; j++) {
            f32x4v z = {0.f, 0.f, 0.f, 0.f};
            acc[i][j] = z;
        }

    uint4  areg[4];
    float4 breg[2];

    /* prologue: stage k-tile 0 */
    #pragma unroll
    for (int i = 0; i < 4; i++) {
        int e = tid * 8 + i * 4096;                    /* A tile, [256][64] */
        areg[i] = *reinterpret_cast<const uint4*>(xs + (size_t)(e >> 6) * D_SZ + (e & 63));
    }
    #pragma unroll
    for (int i = 0; i < 2; i++) {
        int e = tid * 4 + i * 2048;                    /* B tile, [64][64] */
        int n = n0 + (e >> 6);
        const float* src = (n < K_SZ * F_SZ) ? (gw + (size_t)n * D_SZ)
                                             : (uw + (size_t)(n - K_SZ * F_SZ) * D_SZ);
        breg[i] = *reinterpret_cast<const float4*>(src + (e & 63));
    }
    #pragma unroll
    for (int i = 0; i < 4; i++) {
        int e = tid * 8 + i * 4096;
        int r = e >> 6, c = e & 63;
        *reinterpret_cast<uint4*>(&As[0][(r << 6) + SWZ(r, c)]) = areg[i];
    }
    #pragma unroll
    for (int i = 0; i < 2; i++) {
        int e = tid * 4 + i * 2048;
        int r = e >> 6, c = e & 63;
        ushort4 h;
        h.x = f2bf(breg[i].x); h.y = f2bf(breg[i].y);
        h.z = f2bf(breg[i].z); h.w = f2bf(breg[i].w);
        *reinterpret_cast<ushort4*>(&Bs[0][(r << 6) + SWZ(r, c)]) = h;
    }
    __syncthreads();

    int cur = 0;
    #pragma unroll 1
    for (int kt = 0; kt < 16; kt++) {
        if (kt < 15) {
            int k0 = (kt + 1) * 64;
            #pragma unroll
            for (int i = 0; i < 4; i++) {
                int e = tid * 8 + i * 4096;
                areg[i] = *reinterpret_cast<const uint4*>(xs + (size_t)(e >> 6) * D_SZ + k0 + (e & 63));
            }
            #pragma unroll
            for (int i = 0; i < 2; i++) {
                int e = tid * 4 + i * 2048;
                int n = n0 + (e >> 6);
                const float* src = (n < K_SZ * F_SZ) ? (gw + (size_t)n * D_SZ)
                                                     : (uw + (size_t)(n - K_SZ * F_SZ) * D_SZ);
                breg[i] = *reinterpret_cast<const float4*>(src + k0 + (e & 63));
            }
        }
        #pragma unroll
        for (int kk = 0; kk < 2; kk++) {
            const int kof = kk * 32 + (lane >> 4) * 8;
            s16x8v af[4], bfr[2];
            #pragma unroll
            for (int i = 0; i < 4; i++) {
                int row = wm * 64 + i * 16 + (lane & 15);
                af[i] = *reinterpret_cast<const s16x8v*>(&As[cur][(row << 6) + SWZ(row, kof)]);
            }
            #pragma unroll
            for (int j = 0; j < 2; j++) {
                int col = wn * 32 + j * 16 + (lane & 15);
                bfr[j] = *reinterpret_cast<const s16x8v*>(&Bs[cur][(col << 6) + SWZ(col, kof)]);
            }
            #pragma unroll
            for (int i = 0; i < 4; i++)
                #pragma unroll
                for (int j = 0; j < 2; j++)
                    acc[i][j] = __builtin_amdgcn_mfma_f32_16x16x32_bf16(af[i], bfr[j], acc[i][j], 0, 0, 0);
        }
        if (kt < 15) {
            __syncthreads();
            #pragma unroll
            for (int i = 0; i < 4; i++) {
                int e = tid * 8 + i * 4096;
                int r = e >> 6, c = e & 63;
                *reinterpret_cast<uint4*>(&As[cur ^ 1][(r << 6) + SWZ(r, c)]) = areg[i];
            }
            #pragma unroll
            for (int i = 0; i < 2; i++) {
                int e = tid * 4 + i * 2048;
                int r = e >> 6, c = e & 63;
                ushort4 h;
                h.x = f2bf(breg[i].x); h.y = f2bf(breg[i].y);
                h.z = f2bf(breg[i].z); h.w = f2bf(breg[i].w);
                *reinterpret_cast<ushort4*>(&Bs[cur ^ 1][(r << 6) + SWZ(r, c)]) = h;
            }
            __syncthreads();
            cur ^= 1;
        }
    }

    /* epilogue: C/D layout col=lane&15, row=(lane>>4)*4+r */
    const int r0 = (lane >> 4) * 4;
    const int c0 = lane & 15;
    #pragma unroll
    for (int i = 0; i < 4; i++) {
        int rowb = wm * 64 + i * 16 + r0;
        #pragma unroll
        for (int j = 0; j < 2; j++) {
            int col = n0 + wn * 32 + j * 16 + c0;
            #pragma unroll
            for (int r = 0; r < 4; r++)
                bank[(size_t)(rowb + r) * NW + col] = f2bf(acc[i][j][r]);
        }
    }
}

/* ------------------------------------------------------------------ K2:
   hidden[s][b][f] = silu(sum_k gc[s,k]*bank_g[b,k,f]) * sum_k uc[s,k]*bank_u[b,k,f] */
__global__ __launch_bounds__(256)
void k_combine_silu(const unsigned short* __restrict__ bank,
                    const float* __restrict__ gcoef,
                    const float* __restrict__ ucoef,
                    unsigned short* __restrict__ hid) {
    __shared__ float sg[64], su[64];
    int tid = threadIdx.x;
    if (tid < 64) { sg[tid] = gcoef[tid]; su[tid] = ucoef[tid]; }
    __syncthreads();

    int g  = blockIdx.x * 256 + tid;        /* B*F/4 = 262144 */
    int fq = g & (F_SZ / 4 - 1);
    int b  = g >> 10;
    size_t base = (size_t)b * NW + fq * 4;

    float gv[8][4], uv[8][4];
    #pragma unroll
    for (int k = 0; k < 8; k++) {
        ushort4 tg = *reinterpret_cast<const ushort4*>(bank + base + (size_t)k * F_SZ);
        ushort4 tu = *reinterpret_cast<const ushort4*>(bank + base + (size_t)(K_SZ * F_SZ) + (size_t)k * F_SZ);
        gv[k][0] = bf2f(tg.x); gv[k][1] = bf2f(tg.y); gv[k][2] = bf2f(tg.z); gv[k][3] = bf2f(tg.w);
        uv[k][0] = bf2f(tu.x); uv[k][1] = bf2f(tu.y); uv[k][2] = bf2f(tu.z); uv[k][3] = bf2f(tu.w);
    }
    #pragma unroll
    for (int s = 0; s < 8; s++) {
        float go[4] = {0.f, 0.f, 0.f, 0.f}, uo[4] = {0.f, 0.f, 0.f, 0.f};
        #pragma unroll
        for (int k = 0; k < 8; k++) {
            float cg = sg[s * 8 + k], cu = su[s * 8 + k];
            #pragma unroll
            for (int j = 0; j < 4; j++) {
                go[j] = fmaf(cg, gv[k][j], go[j]);
                uo[j] = fmaf(cu, uv[k][j], uo[j]);
            }
        }
        ushort4 h;
        float v0 = (go[0] / (1.f + __expf(-go[0]))) * uo[0];
        float v1 = (go[1] / (1.f + __expf(-go[1]))) * uo[1];
        float v2 = (go[2] / (1.f + __expf(-go[2]))) * uo[2];
        float v3 = (go[3] / (1.f + __expf(-go[3]))) * uo[3];
        h.x = f2bf(v0); h.y = f2bf(v1); h.z = f2bf(v2); h.w = f2bf(v3);
        *reinterpret_cast<ushort4*>(hid + ((size_t)s * B_SZ + b) * F_SZ + fq * 4) = h;
    }
}

/* ------------------------------------------------------------------ K3:
   Wd[s][d][f] = sum_k dc[s,k] * down_w[k][d][f]  (bf16 out) */
__global__ __launch_bounds__(256)
void k_wd_combine(const float* __restrict__ dw,
                  const float* __restrict__ dcoef,
                  unsigned short* __restrict__ wd) {
    __shared__ float sd[64];
    int tid = threadIdx.x;
    if (tid < 64) sd[tid] = dcoef[tid];
    __syncthreads();

    size_t g = (size_t)blockIdx.x * 256 + tid;   /* D*F/4 = 1048576 */
    int fq = (int)(g & (F_SZ / 4 - 1));
    int d  = (int)(g >> 10);

    float wv[8][4];
    #pragma unroll
    for (int k = 0; k < 8; k++) {
        float4 t = *reinterpret_cast<const float4*>(dw + ((size_t)k * D_SZ + d) * F_SZ + fq * 4);
        wv[k][0] = t.x; wv[k][1] = t.y; wv[k][2] = t.z; wv[k][3] = t.w;
    }
    #pragma unroll
    for (int s = 0; s < 8; s++) {
        float o[4] = {0.f, 0.f, 0.f, 0.f};
        #pragma unroll
        for (int k = 0; k < 8; k++) {
            float c = sd[s * 8 + k];
            #pragma unroll
            for (int j = 0; j < 4; j++) o[j] = fmaf(c, wv[k][j], o[j]);
        }
        ushort4 h;
        h.x = f2bf(o[0]); h.y = f2bf(o[1]); h.z = f2bf(o[2]); h.w = f2bf(o[3]);
        *reinterpret_cast<ushort4*>(wd + ((size_t)s * D_SZ + d) * F_SZ + fq * 4) = h;
    }
}

/* ------------------------------------------------------------------ K4:
   out[b][s][d] = sum_f hidden[s][b][f] * Wd[s][d][f]  (fp32 out)
   per s: M=256(b) N=1024(d) K=4096(f). BM=64 BN=64 BK=64, 4 waves (2x2),
   wave tile 32x32. grid (16 nt, 4 bt, 8 s) = 512 blocks; LDS 32 KB ->
   up to 5 blocks/CU resident, independent barrier groups overlap. */
__global__ __launch_bounds__(256)
void k_down_gemm(const unsigned short* __restrict__ hid,
                 const unsigned short* __restrict__ wd,
                 float* __restrict__ out) {
    __shared__ unsigned short As[2][64 * 64];    /* 2 x 8 KB */
    __shared__ unsigned short Bs[2][64 * 64];    /* 2 x 8 KB */

    const int tid  = threadIdx.x;
    const int lane = tid & 63;
    const int wid  = tid >> 6;
    const int wm   = wid >> 1;      /* 0..1 */
    const int wn   = wid & 1;       /* 0..1 */
    const int nt   = blockIdx.x;    /* 16 */
    const int bt   = blockIdx.y;    /* 4  */
    const int s    = blockIdx.z;    /* 8  */

    const unsigned short* Ag = hid + (size_t)s * B_SZ * F_SZ + (size_t)bt * 64 * F_SZ;
    const unsigned short* Bg = wd  + (size_t)s * D_SZ * F_SZ + (size_t)nt * 64 * F_SZ;

    f32x4v acc[2][2];
    #pragma unroll
    for (int i = 0; i < 2; i++)
        #pragma unroll
        for (int j = 0; j < 2; j++) {
            f32x4v z = {0.f, 0.f, 0.f, 0.f};
            acc[i][j] = z;
        }

    uint4 areg[2], breg[2];

    #pragma unroll
    for (int i = 0; i < 2; i++) {
        int e = tid * 8 + i * 2048;       /* [64][64] */
        areg[i] = *reinterpret_cast<const uint4*>(Ag + (size_t)(e >> 6) * F_SZ + (e & 63));
        breg[i] = *reinterpret_cast<const uint4*>(Bg + (size_t)(e >> 6) * F_SZ + (e & 63));
    }
    #pragma unroll
    for (int i = 0; i < 2; i++) {
        int e = tid * 8 + i * 2048;
        int r = e >> 6, c = e & 63;
        *reinterpret_cast<uint4*>(&As[0][(r << 6) + SWZ(r, c)]) = areg[i];
        *reinterpret_cast<uint4*>(&Bs[0][(r << 6) + SWZ(r, c)]) = breg[i];
    }
    __syncthreads();

    int cur = 0;
    #pragma unroll 1
    for (int kt = 0; kt < 64; kt++) {
        if (kt < 63) {
            int k0 = (kt + 1) * 64;
            #pragma unroll
            for (int i = 0; i < 2; i++) {
                int e = tid * 8 + i * 2048;
                areg[i] = *reinterpret_cast<const uint4*>(Ag + (size_t)(e >> 6) * F_SZ + k0 + (e & 63));
                breg[i] = *reinterpret_cast<const uint4*>(Bg + (size_t)(e >> 6) * F_SZ + k0 + (e & 63));
            }
        }
        #pragma unroll
        for (int kk = 0; kk < 2; kk++) {
            const int kof = kk * 32 + (lane >> 4) * 8;
            s16x8v af[2], bfr[2];
            #pragma unroll
            for (int i = 0; i < 2; i++) {
                int row = wm * 32 + i * 16 + (lane & 15);
                af[i] = *reinterpret_cast<const s16x8v*>(&As[cur][(row << 6) + SWZ(row, kof)]);
            }
            #pragma unroll
            for (int j = 0; j < 2; j++) {
                int col = wn * 32 + j * 16 + (lane & 15);
                bfr[j] = *reinterpret_cast<const s16x8v*>(&Bs[cur][(col << 6) + SWZ(col, kof)]);
            }
            #pragma unroll
            for (int i = 0; i < 2; i++)
                #pragma unroll
                for (int j = 0; j < 2; j++)
                    acc[i][j] = __builtin_amdgcn_mfma_f32_16x16x32_bf16(af[i], bfr[j], acc[i][j], 0, 0, 0);
        }
        if (kt < 63) {
            __syncthreads();
            #pragma unroll
            for (int i = 0; i < 2; i++) {
                int e = tid * 8 + i * 2048;
                int r = e >> 6, c = e & 63;
                *reinterpret_cast<uint4*>(&As[cur ^ 1][(r << 6) + SWZ(r, c)]) = areg[i];
                *reinterpret_cast<uint4*>(&Bs[cur ^ 1][(r << 6) + SWZ(r, c)]) = breg[i];
            }
            __syncthreads();
            cur ^= 1;
        }
    }

    const int r0 = (lane >> 4) * 4;
    const int c0 = lane & 15;
    #pragma unroll
    for (int i = 0; i < 2; i++) {
        #pragma unroll
        for (int j = 0; j < 2; j++) {
            #pragma unroll
            for (int r = 0; r < 4; r++) {
                int brow = bt * 64 + wm * 32 + i * 16 + r0 + r;
                int dcol = nt * 64 + wn * 32 + j * 16 + c0;
                out[(size_t)brow * SD + (size_t)s * D_SZ + dcol] = acc[i][j][r];
            }
        }
    }
}

/* ------------------------------------------------------------------ */
extern "C" void kernel_launch(void* const* d_in, const int* in_sizes, int n_in,
                              void* d_out, int out_size, void* d_ws, size_t ws_size,
                              hipStream_t stream) {
    (void)in_sizes; (void)n_in; (void)out_size; (void)ws_size;

    const float* x  = (const float*)d_in[0];
    const float* gw = (const float*)d_in[1];
    const float* uw = (const float*)d_in[2];
    const float* dw = (const float*)d_in[3];
    const float* gc = (const float*)d_in[4];
    const float* uc = (const float*)d_in[5];
    const float* dc = (const float*)d_in[6];
    float* out = (float*)d_out;

    char* ws = (char*)d_ws;
    /* workspace layout (bytes):
       xs_bf16  [256][1024]        @ 0          (   524,288)
       bank     [256][65536] bf16  @ 524288     (33,554,432)
       hidden   [8][256][4096] bf16@ 34078720   (16,777,216)
       Wd       [8][1024][4096]bf16@ 50855936   (67,108,864) */
    unsigned short* xs   = (unsigned short*)(ws);
    unsigned short* bank = (unsigned short*)(ws + 524288);
    unsigned short* hid  = (unsigned short*)(ws + 34078720);
    unsigned short* wdp  = (unsigned short*)(ws + 50855936);

    k_cvt_x       <<<256,  256, 0, stream>>>(x, xs);
    k_bank_gemm   <<<1024, 512, 0, stream>>>(xs, gw, uw, bank);
    k_combine_silu<<<1024, 256, 0, stream>>>(bank, gc, uc, hid);
    k_wd_combine  <<<4096, 256, 0, stream>>>(dw, dc, wdp);
    k_down_gemm   <<<dim3(16, 4, 8), 256, 0, stream>>>(hid, wdp, out);
}

// Round 3
// 586.611 us; speedup vs baseline: 1.1305x; 1.1305x over previous
//
#include <hip/hip_runtime.h>

#define B_SZ 256
#define D_SZ 1024
#define F_SZ 4096
#define K_SZ 8
#define S_SZ 8
#define NW   (2 * K_SZ * F_SZ)   /* 65536 combined gate|up weight rows */
#define SD   (S_SZ * D_SZ)       /* 8192 */

typedef __attribute__((ext_vector_type(4))) float f32x4v;
typedef __attribute__((ext_vector_type(8))) short s16x8v;

/* LDS XOR swizzle (T2): elem col ^= (row&7)<<3 (16B granules across 8 rows) */
#define SWZ(row, col) ((col) ^ (((row) & 7) << 3))

/* raw barrier: NO vmcnt drain (loads stay in flight, counted waits come from
   the compiler's data-dep vmcnt before each ds_write). Only LDS ops drain. */
#define BAR() do {                                            \
    asm volatile("s_waitcnt lgkmcnt(0)" ::: "memory");        \
    __builtin_amdgcn_sched_barrier(0);                        \
    __builtin_amdgcn_s_barrier();                             \
    __builtin_amdgcn_sched_barrier(0);                        \
} while (0)

static __device__ __forceinline__ unsigned short f2bf(float f) {
    union { float f; unsigned u; } v; v.f = f;
    unsigned u = v.u;
    unsigned r = u + 0x7FFFu + ((u >> 16) & 1u);   /* RNE */
    return (unsigned short)(r >> 16);
}
static __device__ __forceinline__ float bf2f(unsigned short h) {
    union { unsigned u; float f; } v; v.u = ((unsigned)h) << 16;
    return v.f;
}

/* ------------------------------------------------------------------ K0:
   convert x (B*D fp32) -> bf16, row-major [256][1024] */
__global__ __launch_bounds__(256) void k_cvt_x(const float* __restrict__ x,
                                               unsigned short* __restrict__ xs) {
    int g = blockIdx.x * 256 + threadIdx.x;
    float4 v = reinterpret_cast<const float4*>(x)[g];
    ushort4 h;
    h.x = f2bf(v.x); h.y = f2bf(v.y); h.z = f2bf(v.z); h.w = f2bf(v.w);
    reinterpret_cast<ushort4*>(xs)[g] = h;
}

/* ------------------------------------------------------------------ K1:
   bank[256][65536] (bf16) = xs[256][1024] @ W^T, W = [gate_w; up_w] fp32.
   BM=256, BN=128, BK=64. 512 thr = 8 waves (4M x 2N), wave tile 64x64.
   Counted-vmcnt pipeline: 2-deep reg prefetch (named sets, rule #20),
   raw s_barrier (no vmcnt drain), ONE barrier per K-step. NO launch_bounds
   reg cap (round-2 spill lesson: VGPR 52 -> 292 MB scratch writes). */
__global__ __launch_bounds__(512)
void k_bank_gemm(const unsigned short* __restrict__ xs,
                 const float* __restrict__ gw,
                 const float* __restrict__ uw,
                 unsigned short* __restrict__ bank) {
    __shared__ unsigned short As[2][256 * 64];   /* 2 x 32 KB */
    __shared__ unsigned short Bs[2][128 * 64];   /* 2 x 16 KB */

    const int tid  = threadIdx.x;
    const int lane = tid & 63;
    const int wid  = tid >> 6;
    const int wm   = wid >> 1;          /* 0..3 */
    const int wn   = wid & 1;           /* 0..1 */
    const int n0   = blockIdx.x * 128;

    /* constant per-thread staging coords */
    const int ar = tid >> 3;            /* A row base, +i*64  */
    const int ac = (tid * 8) & 63;
    const int br = tid >> 4;            /* B row base, +i*32  */
    const int bc = (tid * 4) & 63;

    f32x4v acc[4][4];
    #pragma unroll
    for (int i = 0; i < 4; i++)
        #pragma unroll
        for (int j = 0; j < 4; j++) {
            f32x4v z = {0.f, 0.f, 0.f, 0.f};
            acc[i][j] = z;
        }

    uint4  a0[4], a1[4];
    float4 b0[4], b1[4];

#define K1_LOAD_A(dst, kt) do { _Pragma("unroll")                              \
    for (int i = 0; i < 4; i++)                                                \
        dst[i] = *reinterpret_cast<const uint4*>(                              \
            xs + (size_t)(ar + i * 64) * D_SZ + (kt) * 64 + ac); } while (0)

#define K1_LOAD_B(dst, kt) do { _Pragma("unroll")                              \
    for (int i = 0; i < 4; i++) {                                              \
        int n = n0 + br + i * 32;                                              \
        const float* src = (n < K_SZ * F_SZ)                                   \
            ? (gw + (size_t)n * D_SZ)                                          \
            : (uw + (size_t)(n - K_SZ * F_SZ) * D_SZ);                         \
        dst[i] = *reinterpret_cast<const float4*>(src + (kt) * 64 + bc);       \
    } } while (0)

#define K1_WRITE_A(buf, src) do { _Pragma("unroll")                            \
    for (int i = 0; i < 4; i++) {                                              \
        int r = ar + i * 64;                                                   \
        *reinterpret_cast<uint4*>(&As[buf][(r << 6) + SWZ(r, ac)]) = src[i];   \
    } } while (0)

#define K1_WRITE_B(buf, src) do { _Pragma("unroll")                            \
    for (int i = 0; i < 4; i++) {                                              \
        int r = br + i * 32; ushort4 h;                                        \
        h.x = f2bf(src[i].x); h.y = f2bf(src[i].y);                            \
        h.z = f2bf(src[i].z); h.w = f2bf(src[i].w);                            \
        *reinterpret_cast<ushort4*>(&Bs[buf][(r << 6) + SWZ(r, bc)]) = h;      \
    } } while (0)

#define K1_COMPUTE(buf) do { _Pragma("unroll")                                 \
    for (int kk = 0; kk < 2; kk++) {                                           \
        const int kof = kk * 32 + (lane >> 4) * 8;                             \
        s16x8v af[4], bfv[4];                                                  \
        _Pragma("unroll") for (int i = 0; i < 4; i++) {                        \
            int row = wm * 64 + i * 16 + (lane & 15);                          \
            af[i] = *reinterpret_cast<const s16x8v*>(                          \
                &As[buf][(row << 6) + SWZ(row, kof)]); }                       \
        _Pragma("unroll") for (int j = 0; j < 4; j++) {                        \
            int col = wn * 64 + j * 16 + (lane & 15);                          \
            bfv[j] = *reinterpret_cast<const s16x8v*>(                         \
                &Bs[buf][(col << 6) + SWZ(col, kof)]); }                       \
        _Pragma("unroll") for (int i = 0; i < 4; i++)                          \
            _Pragma("unroll") for (int j = 0; j < 4; j++)                      \
                acc[i][j] = __builtin_amdgcn_mfma_f32_16x16x32_bf16(           \
                    af[i], bfv[j], acc[i][j], 0, 0, 0);                        \
    } } while (0)

    /* prologue: kt0 -> set0 -> LDS0; kt1 -> set1 (in flight) */
    K1_LOAD_A(a0, 0); K1_LOAD_B(b0, 0);
    K1_LOAD_A(a1, 1); K1_LOAD_B(b1, 1);
    K1_WRITE_A(0, a0); K1_WRITE_B(0, b0);
    BAR();

    #pragma unroll 1
    for (int kt2 = 0; kt2 < 8; kt2++) {
        const int kt = kt2 * 2;
        /* even step: compute buf0 (kt), prefetch kt+2 -> set0, write set1(kt+1) -> buf1 */
        if (kt + 2 < 16) { K1_LOAD_A(a0, kt + 2); K1_LOAD_B(b0, kt + 2); }
        K1_COMPUTE(0);
        K1_WRITE_A(1, a1); K1_WRITE_B(1, b1);   /* auto vmcnt keeps set0 loads in flight */
        BAR();
        /* odd step: compute buf1 (kt+1), prefetch kt+3 -> set1, write set0(kt+2) -> buf0 */
        if (kt + 3 < 16) { K1_LOAD_A(a1, kt + 3); K1_LOAD_B(b1, kt + 3); }
        K1_COMPUTE(1);
        if (kt + 2 < 16) {
            K1_WRITE_A(0, a0); K1_WRITE_B(0, b0);
            BAR();
        }
    }

    /* epilogue: C/D layout col=lane&15, row=(lane>>4)*4+r (m89-verified) */
    const int r0 = (lane >> 4) * 4;
    const int c0 = lane & 15;
    #pragma unroll
    for (int i = 0; i < 4; i++) {
        int rowb = wm * 64 + i * 16 + r0;
        #pragma unroll
        for (int j = 0; j < 4; j++) {
            int col = n0 + wn * 64 + j * 16 + c0;
            #pragma unroll
            for (int r = 0; r < 4; r++)
                bank[(size_t)(rowb + r) * NW + col] = f2bf(acc[i][j][r]);
        }
    }
#undef K1_LOAD_A
#undef K1_LOAD_B
#undef K1_WRITE_A
#undef K1_WRITE_B
#undef K1_COMPUTE
}

/* ------------------------------------------------------------------ K2:
   hidden[s][b][f] = silu(sum_k gc[s,k]*bank_g[b,k,f]) * sum_k uc[s,k]*bank_u[b,k,f] */
__global__ __launch_bounds__(256)
void k_combine_silu(const unsigned short* __restrict__ bank,
                    const float* __restrict__ gcoef,
                    const float* __restrict__ ucoef,
                    unsigned short* __restrict__ hid) {
    __shared__ float sg[64], su[64];
    int tid = threadIdx.x;
    if (tid < 64) { sg[tid] = gcoef[tid]; su[tid] = ucoef[tid]; }
    __syncthreads();

    int g  = blockIdx.x * 256 + tid;        /* B*F/4 = 262144 */
    int fq = g & (F_SZ / 4 - 1);
    int b  = g >> 10;
    size_t base = (size_t)b * NW + fq * 4;

    float gv[8][4], uv[8][4];
    #pragma unroll
    for (int k = 0; k < 8; k++) {
        ushort4 tg = *reinterpret_cast<const ushort4*>(bank + base + (size_t)k * F_SZ);
        ushort4 tu = *reinterpret_cast<const ushort4*>(bank + base + (size_t)(K_SZ * F_SZ) + (size_t)k * F_SZ);
        gv[k][0] = bf2f(tg.x); gv[k][1] = bf2f(tg.y); gv[k][2] = bf2f(tg.z); gv[k][3] = bf2f(tg.w);
        uv[k][0] = bf2f(tu.x); uv[k][1] = bf2f(tu.y); uv[k][2] = bf2f(tu.z); uv[k][3] = bf2f(tu.w);
    }
    #pragma unroll
    for (int s = 0; s < 8; s++) {
        float go[4] = {0.f, 0.f, 0.f, 0.f}, uo[4] = {0.f, 0.f, 0.f, 0.f};
        #pragma unroll
        for (int k = 0; k < 8; k++) {
            float cg = sg[s * 8 + k], cu = su[s * 8 + k];
            #pragma unroll
            for (int j = 0; j < 4; j++) {
                go[j] = fmaf(cg, gv[k][j], go[j]);
                uo[j] = fmaf(cu, uv[k][j], uo[j]);
            }
        }
        ushort4 h;
        float v0 = (go[0] / (1.f + __expf(-go[0]))) * uo[0];
        float v1 = (go[1] / (1.f + __expf(-go[1]))) * uo[1];
        float v2 = (go[2] / (1.f + __expf(-go[2]))) * uo[2];
        float v3 = (go[3] / (1.f + __expf(-go[3]))) * uo[3];
        h.x = f2bf(v0); h.y = f2bf(v1); h.z = f2bf(v2); h.w = f2bf(v3);
        *reinterpret_cast<ushort4*>(hid + ((size_t)s * B_SZ + b) * F_SZ + fq * 4) = h;
    }
}

/* ------------------------------------------------------------------ K3:
   Wd[s][d][f] = sum_k dc[s,k] * down_w[k][d][f]  (bf16 out) */
__global__ __launch_bounds__(256)
void k_wd_combine(const float* __restrict__ dw,
                  const float* __restrict__ dcoef,
                  unsigned short* __restrict__ wd) {
    __shared__ float sd[64];
    int tid = threadIdx.x;
    if (tid < 64) sd[tid] = dcoef[tid];
    __syncthreads();

    size_t g = (size_t)blockIdx.x * 256 + tid;   /* D*F/4 = 1048576 */
    int fq = (int)(g & (F_SZ / 4 - 1));
    int d  = (int)(g >> 10);

    float wv[8][4];
    #pragma unroll
    for (int k = 0; k < 8; k++) {
        float4 t = *reinterpret_cast<const float4*>(dw + ((size_t)k * D_SZ + d) * F_SZ + fq * 4);
        wv[k][0] = t.x; wv[k][1] = t.y; wv[k][2] = t.z; wv[k][3] = t.w;
    }
    #pragma unroll
    for (int s = 0; s < 8; s++) {
        float o[4] = {0.f, 0.f, 0.f, 0.f};
        #pragma unroll
        for (int k = 0; k < 8; k++) {
            float c = sd[s * 8 + k];
            #pragma unroll
            for (int j = 0; j < 4; j++) o[j] = fmaf(c, wv[k][j], o[j]);
        }
        ushort4 h;
        h.x = f2bf(o[0]); h.y = f2bf(o[1]); h.z = f2bf(o[2]); h.w = f2bf(o[3]);
        *reinterpret_cast<ushort4*>(wd + ((size_t)s * D_SZ + d) * F_SZ + fq * 4) = h;
    }
}

/* ------------------------------------------------------------------ K4:
   out[b][s][d] = sum_f hidden[s][b][f] * Wd[s][d][f]  (fp32 out)
   per s: M=256(b) N=1024(d) K=4096(f). BM=64 BN=64 BK=128. 256 thr =
   4 waves (2x2), wave tile 32x32. grid (16 nt, 4 bt, 8 s) = 512 blocks,
   LDS 64 KB -> 2 blocks/CU. Same counted-vmcnt pipeline as K1. */
__global__ __launch_bounds__(256)
void k_down_gemm(const unsigned short* __restrict__ hid,
                 const unsigned short* __restrict__ wd,
                 float* __restrict__ out) {
    __shared__ unsigned short As[2][64 * 128];   /* 2 x 16 KB */
    __shared__ unsigned short Bs[2][64 * 128];   /* 2 x 16 KB */

    const int tid  = threadIdx.x;
    const int lane = tid & 63;
    const int wid  = tid >> 6;
    const int wm   = wid >> 1;      /* 0..1 */
    const int wn   = wid & 1;       /* 0..1 */
    const int nt   = blockIdx.x;    /* 16 */
    const int bt   = blockIdx.y;    /* 4  */
    const int s    = blockIdx.z;    /* 8  */

    const unsigned short* Ag = hid + (size_t)s * B_SZ * F_SZ + (size_t)bt * 64 * F_SZ;
    const unsigned short* Bg = wd  + (size_t)s * D_SZ * F_SZ + (size_t)nt * 64 * F_SZ;

    const int sr = tid >> 4;            /* staging row base, +i*16 */
    const int sc = (tid * 8) & 127;     /* staging col (8-elem aligned) */

    f32x4v acc[2][2];
    #pragma unroll
    for (int i = 0; i < 2; i++)
        #pragma unroll
        for (int j = 0; j < 2; j++) {
            f32x4v z = {0.f, 0.f, 0.f, 0.f};
            acc[i][j] = z;
        }

    uint4 a0[4], a1[4], b0[4], b1[4];

#define K4_LOAD(dstA, dstB, kt) do { _Pragma("unroll")                         \
    for (int i = 0; i < 4; i++) {                                              \
        int r = sr + i * 16;                                                   \
        dstA[i] = *reinterpret_cast<const uint4*>(                             \
            Ag + (size_t)r * F_SZ + (kt) * 128 + sc);                          \
        dstB[i] = *reinterpret_cast<const uint4*>(                             \
            Bg + (size_t)r * F_SZ + (kt) * 128 + sc);                          \
    } } while (0)

#define K4_WRITE(buf, srcA, srcB) do { _Pragma("unroll")                       \
    for (int i = 0; i < 4; i++) {                                              \
        int r = sr + i * 16;                                                   \
        *reinterpret_cast<uint4*>(&As[buf][(r << 7) + SWZ(r, sc)]) = srcA[i];  \
        *reinterpret_cast<uint4*>(&Bs[buf][(r << 7) + SWZ(r, sc)]) = srcB[i];  \
    } } while (0)

#define K4_COMPUTE(buf) do { _Pragma("unroll")                                 \
    for (int kk = 0; kk < 4; kk++) {                                           \
        const int kof = kk * 32 + (lane >> 4) * 8;                             \
        s16x8v af[2], bfv[2];                                                  \
        _Pragma("unroll") for (int i = 0; i < 2; i++) {                        \
            int row = wm * 32 + i * 16 + (lane & 15);                          \
            af[i] = *reinterpret_cast<const s16x8v*>(                          \
                &As[buf][(row << 7) + SWZ(row, kof)]); }                       \
        _Pragma("unroll") for (int j = 0; j < 2; j++) {                        \
            int col = wn * 32 + j * 16 + (lane & 15);                          \
            bfv[j] = *reinterpret_cast<const s16x8v*>(                         \
                &Bs[buf][(col << 7) + SWZ(col, kof)]); }                       \
        _Pragma("unroll") for (int i = 0; i < 2; i++)                          \
            _Pragma("unroll") for (int j = 0; j < 2; j++)                      \
                acc[i][j] = __builtin_amdgcn_mfma_f32_16x16x32_bf16(           \
                    af[i], bfv[j], acc[i][j], 0, 0, 0);                        \
    } } while (0)

    /* 32 K-tiles of 128 */
    K4_LOAD(a0, b0, 0);
    K4_LOAD(a1, b1, 1);
    K4_WRITE(0, a0, b0);
    BAR();

    #pragma unroll 1
    for (int kt2 = 0; kt2 < 16; kt2++) {
        const int kt = kt2 * 2;
        if (kt + 2 < 32) K4_LOAD(a0, b0, kt + 2);
        K4_COMPUTE(0);
        K4_WRITE(1, a1, b1);
        BAR();
        if (kt + 3 < 32) K4_LOAD(a1, b1, kt + 3);
        K4_COMPUTE(1);
        if (kt + 2 < 32) {
            K4_WRITE(0, a0, b0);
            BAR();
        }
    }

    const int r0 = (lane >> 4) * 4;
    const int c0 = lane & 15;
    #pragma unroll
    for (int i = 0; i < 2; i++) {
        #pragma unroll
        for (int j = 0; j < 2; j++) {
            #pragma unroll
            for (int r = 0; r < 4; r++) {
                int brow = bt * 64 + wm * 32 + i * 16 + r0 + r;
                int dcol = nt * 64 + wn * 32 + j * 16 + c0;
                out[(size_t)brow * SD + (size_t)s * D_SZ + dcol] = acc[i][j][r];
            }
        }
    }
#undef K4_LOAD
#undef K4_WRITE
#undef K4_COMPUTE
}

/* ------------------------------------------------------------------ */
extern "C" void kernel_launch(void* const* d_in, const int* in_sizes, int n_in,
                              void* d_out, int out_size, void* d_ws, size_t ws_size,
                              hipStream_t stream) {
    (void)in_sizes; (void)n_in; (void)out_size; (void)ws_size;

    const float* x  = (const float*)d_in[0];
    const float* gw = (const float*)d_in[1];
    const float* uw = (const float*)d_in[2];
    const float* dw = (const float*)d_in[3];
    const float* gc = (const float*)d_in[4];
    const float* uc = (const float*)d_in[5];
    const float* dc = (const float*)d_in[6];
    float* out = (float*)d_out;

    char* ws = (char*)d_ws;
    /* workspace layout (bytes):
       xs_bf16  [256][1024]        @ 0          (   524,288)
       bank     [256][65536] bf16  @ 524288     (33,554,432)
       hidden   [8][256][4096] bf16@ 34078720   (16,777,216)
       Wd       [8][1024][4096]bf16@ 50855936   (67,108,864) */
    unsigned short* xs   = (unsigned short*)(ws);
    unsigned short* bank = (unsigned short*)(ws + 524288);
    unsigned short* hid  = (unsigned short*)(ws + 34078720);
    unsigned short* wdp  = (unsigned short*)(ws + 50855936);

    k_cvt_x       <<<256,  256, 0, stream>>>(x, xs);
    k_bank_gemm   <<<512,  512, 0, stream>>>(xs, gw, uw, bank);
    k_combine_silu<<<1024, 256, 0, stream>>>(bank, gc, uc, hid);
    k_wd_combine  <<<4096, 256, 0, stream>>>(dw, dc, wdp);
    k_down_gemm   <<<dim3(16, 4, 8), 256, 0, stream>>>(hid, wdp, out);
}

// Round 8
// 472.713 us; speedup vs baseline: 1.4029x; 1.2409x over previous
//
#include <hip/hip_runtime.h>

#define B_SZ 256
#define D_SZ 1024
#define F_SZ 4096
#define K_SZ 8
#define S_SZ 8
#define NW   (2 * K_SZ * F_SZ)   /* 65536 combined gate|up weight rows */
#define SD   (S_SZ * D_SZ)       /* 8192 */

typedef __attribute__((ext_vector_type(4))) float f32x4v;
typedef __attribute__((ext_vector_type(8))) short s16x8v;

typedef __attribute__((address_space(1))) const unsigned int  gas_u32;
typedef __attribute__((address_space(3))) unsigned int        las_u32;

static __device__ __forceinline__ unsigned short f2bf(float f) {
    union { float f; unsigned u; } v; v.f = f;
    unsigned u = v.u;
    unsigned r = u + 0x7FFFu + ((u >> 16) & 1u);   /* RNE */
    return (unsigned short)(r >> 16);
}
static __device__ __forceinline__ float bf2f(unsigned short h) {
    union { unsigned u; float f; } v; v.u = ((unsigned)h) << 16;
    return v.f;
}

/* ------------------------------------------------------------------ K0:
   convert x (B*D fp32) -> bf16, row-major [256][1024] */
__global__ __launch_bounds__(256) void k_cvt_x(const float* __restrict__ x,
                                               unsigned short* __restrict__ xs) {
    int g = blockIdx.x * 256 + threadIdx.x;
    float4 v = reinterpret_cast<const float4*>(x)[g];
    ushort4 h;
    h.x = f2bf(v.x); h.y = f2bf(v.y); h.z = f2bf(v.z); h.w = f2bf(v.w);
    reinterpret_cast<ushort4*>(xs)[g] = h;
}

/* ------------------------------------------------------------------ K1:
   bank[256][65536] (bf16) = xs[256][1024] @ W^T, W = [gate_w; up_w] fp32.
   BM=256, BN=64, BK=64. 512 thr = 8 waves (4M x 2N), wave tile 64x32.
   A staged via global_load_lds DMA (zero VGPR pressure, in-flight tile
   lives in the vmcnt queue -- round-2/3 spill lesson). B reg-staged
   single-set (fp32->bf16 conversion forces the VGPR round-trip).
   LDS 80 KB -> 2 blocks/CU. m97-proven 2-phase:
   STAGE(next) -> COMPUTE(cur) -> one __syncthreads. */
__global__ __launch_bounds__(512)
void k_bank_gemm(const unsigned short* __restrict__ xs,
                 const float* __restrict__ gw,
                 const float* __restrict__ uw,
                 unsigned short* __restrict__ bank) {
    __shared__ unsigned short As[2][256 * 64];   /* 2 x 32 KB */
    __shared__ unsigned short Bs[2][64 * 64];    /* 2 x  8 KB */

    const int tid  = threadIdx.x;
    const int lane = tid & 63;
    const int wid  = tid >> 6;          /* 0..7 */
    const int wm   = wid >> 1;          /* 0..3 */
    const int wn   = wid & 1;           /* 0..1 */
    const int n0   = blockIdx.x * 64;

    /* A DMA mapping: wave issue i covers tile bytes [(wid*4+i)*1024 + lane*16).
       row = (wid*4+i)*8 + lane/8, col elems = (lane&7)*8. Dest is wave-uniform
       base; HW adds lane*16. */
    const int a_row = wid * 32 + (lane >> 3);    /* + i*8 */
    const int a_col = (lane & 7) * 8;
    /* B reg staging: thread -> 2 x float4; row = tid/16 + i*32, col = (tid&15)*4 */
    const int b_row = tid >> 4;
    const int b_col = (tid & 15) * 4;

    f32x4v acc[4][2];
    #pragma unroll
    for (int i = 0; i < 4; i++)
        #pragma unroll
        for (int j = 0; j < 2; j++) {
            f32x4v z = {0.f, 0.f, 0.f, 0.f};
            acc[i][j] = z;
        }

    float4 breg[2];

#define K1_STAGE_A(buf, kt) do { _Pragma("unroll")                             \
    for (int i = 0; i < 4; i++) {                                              \
        const unsigned short* g = xs + (size_t)(a_row + i * 8) * D_SZ          \
                                     + (kt) * 64 + a_col;                      \
        __builtin_amdgcn_global_load_lds(                                      \
            (gas_u32*)g, (las_u32*)&As[buf][(wid * 4 + i) * 512], 16, 0, 0);   \
    } } while (0)

#define K1_LOAD_B(kt) do { _Pragma("unroll")                                   \
    for (int i = 0; i < 2; i++) {                                              \
        int n = n0 + b_row + i * 32;                                           \
        const float* src = (n < K_SZ * F_SZ)                                   \
            ? (gw + (size_t)n * D_SZ)                                          \
            : (uw + (size_t)(n - K_SZ * F_SZ) * D_SZ);                         \
        breg[i] = *reinterpret_cast<const float4*>(src + (kt) * 64 + b_col);   \
    } } while (0)

#define K1_WRITE_B(buf) do { _Pragma("unroll")                                 \
    for (int i = 0; i < 2; i++) {                                              \
        ushort4 h;                                                             \
        h.x = f2bf(breg[i].x); h.y = f2bf(breg[i].y);                          \
        h.z = f2bf(breg[i].z); h.w = f2bf(breg[i].w);                          \
        *reinterpret_cast<ushort4*>(                                           \
            &Bs[buf][(b_row + i * 32) * 64 + b_col]) = h;                      \
    } } while (0)

#define K1_COMPUTE(buf) do { _Pragma("unroll")                                 \
    for (int kk = 0; kk < 2; kk++) {                                           \
        const int kof = kk * 32 + (lane >> 4) * 8;                             \
        s16x8v af[4], bfv[2];                                                  \
        _Pragma("unroll") for (int i = 0; i < 4; i++) {                        \
            int row = wm * 64 + i * 16 + (lane & 15);                          \
            af[i] = *reinterpret_cast<const s16x8v*>(&As[buf][row * 64 + kof]); } \
        _Pragma("unroll") for (int j = 0; j < 2; j++) {                        \
            int col = wn * 32 + j * 16 + (lane & 15);                          \
            bfv[j] = *reinterpret_cast<const s16x8v*>(&Bs[buf][col * 64 + kof]); } \
        _Pragma("unroll") for (int i = 0; i < 4; i++)                          \
            _Pragma("unroll") for (int j = 0; j < 2; j++)                      \
                acc[i][j] = __builtin_amdgcn_mfma_f32_16x16x32_bf16(           \
                    af[i], bfv[j], acc[i][j], 0, 0, 0);                        \
    } } while (0)

    /* prologue */
    K1_STAGE_A(0, 0);
    K1_LOAD_B(0);
    K1_WRITE_B(0);
    __syncthreads();

    #pragma unroll 1
    for (int kt = 0; kt < 16; kt++) {
        const int cur = kt & 1;
        if (kt + 1 < 16) {
            K1_STAGE_A(cur ^ 1, kt + 1);   /* DMA next tile, stays in flight */
            K1_LOAD_B(kt + 1);
        }
        K1_COMPUTE(cur);
        if (kt + 1 < 16) {
            K1_WRITE_B(cur ^ 1);
            __syncthreads();               /* drains DMA + ds_writes */
        }
    }

    /* epilogue: C/D layout col=lane&15, row=(lane>>4)*4+r (m89-verified) */
    const int r0 = (lane >> 4) * 4;
    const int c0 = lane & 15;
    #pragma unroll
    for (int i = 0; i < 4; i++) {
        int rowb = wm * 64 + i * 16 + r0;
        #pragma unroll
        for (int j = 0; j < 2; j++) {
            int col = n0 + wn * 32 + j * 16 + c0;
            #pragma unroll
            for (int r = 0; r < 4; r++)
                bank[(size_t)(rowb + r) * NW + col] = f2bf(acc[i][j][r]);
        }
    }
#undef K1_STAGE_A
#undef K1_LOAD_B
#undef K1_WRITE_B
#undef K1_COMPUTE
}

/* ------------------------------------------------------------------ K2:
   hidden[s][b][f] = silu(sum_k gc[s,k]*bank_g[b,k,f]) * sum_k uc[s,k]*bank_u[b,k,f] */
__global__ __launch_bounds__(256)
void k_combine_silu(const unsigned short* __restrict__ bank,
                    const float* __restrict__ gcoef,
                    const float* __restrict__ ucoef,
                    unsigned short* __restrict__ hid) {
    __shared__ float sg[64], su[64];
    int tid = threadIdx.x;
    if (tid < 64) { sg[tid] = gcoef[tid]; su[tid] = ucoef[tid]; }
    __syncthreads();

    int g  = blockIdx.x * 256 + tid;        /* B*F/4 = 262144 */
    int fq = g & (F_SZ / 4 - 1);
    int b  = g >> 10;
    size_t base = (size_t)b * NW + fq * 4;

    float gv[8][4], uv[8][4];
    #pragma unroll
    for (int k = 0; k < 8; k++) {
        ushort4 tg = *reinterpret_cast<const ushort4*>(bank + base + (size_t)k * F_SZ);
        ushort4 tu = *reinterpret_cast<const ushort4*>(bank + base + (size_t)(K_SZ * F_SZ) + (size_t)k * F_SZ);
        gv[k][0] = bf2f(tg.x); gv[k][1] = bf2f(tg.y); gv[k][2] = bf2f(tg.z); gv[k][3] = bf2f(tg.w);
        uv[k][0] = bf2f(tu.x); uv[k][1] = bf2f(tu.y); uv[k][2] = bf2f(tu.z); uv[k][3] = bf2f(tu.w);
    }
    #pragma unroll
    for (int s = 0; s < 8; s++) {
        float go[4] = {0.f, 0.f, 0.f, 0.f}, uo[4] = {0.f, 0.f, 0.f, 0.f};
        #pragma unroll
        for (int k = 0; k < 8; k++) {
            float cg = sg[s * 8 + k], cu = su[s * 8 + k];
            #pragma unroll
            for (int j = 0; j < 4; j++) {
                go[j] = fmaf(cg, gv[k][j], go[j]);
                uo[j] = fmaf(cu, uv[k][j], uo[j]);
            }
        }
        ushort4 h;
        float v0 = (go[0] / (1.f + __expf(-go[0]))) * uo[0];
        float v1 = (go[1] / (1.f + __expf(-go[1]))) * uo[1];
        float v2 = (go[2] / (1.f + __expf(-go[2]))) * uo[2];
        float v3 = (go[3] / (1.f + __expf(-go[3]))) * uo[3];
        h.x = f2bf(v0); h.y = f2bf(v1); h.z = f2bf(v2); h.w = f2bf(v3);
        *reinterpret_cast<ushort4*>(hid + ((size_t)s * B_SZ + b) * F_SZ + fq * 4) = h;
    }
}

/* ------------------------------------------------------------------ K3:
   Wd[s][d][f] = sum_k dc[s,k] * down_w[k][d][f]  (bf16 out) */
__global__ __launch_bounds__(256)
void k_wd_combine(const float* __restrict__ dw,
                  const float* __restrict__ dcoef,
                  unsigned short* __restrict__ wd) {
    __shared__ float sd[64];
    int tid = threadIdx.x;
    if (tid < 64) sd[tid] = dcoef[tid];
    __syncthreads();

    size_t g = (size_t)blockIdx.x * 256 + tid;   /* D*F/4 = 1048576 */
    int fq = (int)(g & (F_SZ / 4 - 1));
    int d  = (int)(g >> 10);

    float wv[8][4];
    #pragma unroll
    for (int k = 0; k < 8; k++) {
        float4 t = *reinterpret_cast<const float4*>(dw + ((size_t)k * D_SZ + d) * F_SZ + fq * 4);
        wv[k][0] = t.x; wv[k][1] = t.y; wv[k][2] = t.z; wv[k][3] = t.w;
    }
    #pragma unroll
    for (int s = 0; s < 8; s++) {
        float o[4] = {0.f, 0.f, 0.f, 0.f};
        #pragma unroll
        for (int k = 0; k < 8; k++) {
            float c = sd[s * 8 + k];
            #pragma unroll
            for (int j = 0; j < 4; j++) o[j] = fmaf(c, wv[k][j], o[j]);
        }
        ushort4 h;
        h.x = f2bf(o[0]); h.y = f2bf(o[1]); h.z = f2bf(o[2]); h.w = f2bf(o[3]);
        *reinterpret_cast<ushort4*>(wd + ((size_t)s * D_SZ + d) * F_SZ + fq * 4) = h;
    }
}

/* ------------------------------------------------------------------ K4:
   out[b][s][d] = sum_f hidden[s][b][f] * Wd[s][d][f]  (fp32 out)
   per s: M=256(b) N=1024(d) K=4096(f). BM=64 BN=64 BK=64, 256 thr =
   4 waves (2x2), wave tile 32x32. Both operands bf16 -> pure
   global_load_lds staging (zero VGPR staging). LDS 32 KB -> 4 blocks/CU.
   Grid = flat 512 with XCD-chunked swizzle (T1): logical work
   wgid = bt + 4*nt + 64*s, remapped so works [64c, 64c+64) land on XCD c;
   the 4 bt-blocks sharing one 512 KB Wd panel become L2-co-resident, and
   hid[s] (2 MB) stays L2-resident per XCD. */
__global__ __launch_bounds__(256)
void k_down_gemm(const unsigned short* __restrict__ hid,
                 const unsigned short* __restrict__ wd,
                 float* __restrict__ out) {
    __shared__ unsigned short As[2][64 * 64];    /* 2 x 8 KB */
    __shared__ unsigned short Bs[2][64 * 64];    /* 2 x 8 KB */

    const int tid  = threadIdx.x;
    const int lane = tid & 63;
    const int wid  = tid >> 6;      /* 0..3 */
    const int wm   = wid >> 1;      /* 0..1 */
    const int wn   = wid & 1;       /* 0..1 */

    /* XCD-chunked bijective swizzle: 512 blocks, 8 XCDs, 64 works per XCD. */
    const int orig = blockIdx.x;                  /* hw id: xcd = orig % 8 */
    const int wgid = (orig & 7) * 64 + (orig >> 3);
    const int bt   = wgid & 3;                    /* 4  */
    const int nt   = (wgid >> 2) & 15;            /* 16 */
    const int s    = wgid >> 6;                   /* 8  */

    const unsigned short* Ag = hid + (size_t)s * B_SZ * F_SZ + (size_t)bt * 64 * F_SZ;
    const unsigned short* Bg = wd  + (size_t)s * D_SZ * F_SZ + (size_t)nt * 64 * F_SZ;

    /* DMA mapping for a [64][64] bf16 tile (8 KB): wave issue i covers bytes
       [(wid*2+i)*1024 + lane*16): row = (wid*2+i)*8 + lane/8, col = (lane&7)*8 */
    const int s_row = wid * 16 + (lane >> 3);    /* + i*8 */
    const int s_col = (lane & 7) * 8;

    f32x4v acc[2][2];
    #pragma unroll
    for (int i = 0; i < 2; i++)
        #pragma unroll
        for (int j = 0; j < 2; j++) {
            f32x4v z = {0.f, 0.f, 0.f, 0.f};
            acc[i][j] = z;
        }

#define K4_STAGE(buf, kt) do { _Pragma("unroll")                               \
    for (int i = 0; i < 2; i++) {                                              \
        int row = s_row + i * 8;                                               \
        const unsigned short* ga = Ag + (size_t)row * F_SZ + (kt) * 64 + s_col;\
        const unsigned short* gb = Bg + (size_t)row * F_SZ + (kt) * 64 + s_col;\
        __builtin_amdgcn_global_load_lds(                                      \
            (gas_u32*)ga, (las_u32*)&As[buf][(wid * 2 + i) * 512], 16, 0, 0);  \
        __builtin_amdgcn_global_load_lds(                                      \
            (gas_u32*)gb, (las_u32*)&Bs[buf][(wid * 2 + i) * 512], 16, 0, 0);  \
    } } while (0)

#define K4_COMPUTE(buf) do { _Pragma("unroll")                                 \
    for (int kk = 0; kk < 2; kk++) {                                           \
        const int kof = kk * 32 + (lane >> 4) * 8;                             \
        s16x8v af[2], bfv[2];                                                  \
        _Pragma("unroll") for (int i = 0; i < 2; i++) {                        \
            int row = wm * 32 + i * 16 + (lane & 15);                          \
            af[i] = *reinterpret_cast<const s16x8v*>(&As[buf][row * 64 + kof]); } \
        _Pragma("unroll") for (int j = 0; j < 2; j++) {                        \
            int col = wn * 32 + j * 16 + (lane & 15);                          \
            bfv[j] = *reinterpret_cast<const s16x8v*>(&Bs[buf][col * 64 + kof]); } \
        _Pragma("unroll") for (int i = 0; i < 2; i++)                          \
            _Pragma("unroll") for (int j = 0; j < 2; j++)                      \
                acc[i][j] = __builtin_amdgcn_mfma_f32_16x16x32_bf16(           \
                    af[i], bfv[j], acc[i][j], 0, 0, 0);                        \
    } } while (0)

    K4_STAGE(0, 0);
    __syncthreads();

    #pragma unroll 1
    for (int kt = 0; kt < 64; kt++) {
        const int cur = kt & 1;
        if (kt + 1 < 64) K4_STAGE(cur ^ 1, kt + 1);   /* DMA next, in flight */
        K4_COMPUTE(cur);
        if (kt + 1 < 64) __syncthreads();
    }

    const int r0 = (lane >> 4) * 4;
    const int c0 = lane & 15;
    #pragma unroll
    for (int i = 0; i < 2; i++) {
        #pragma unroll
        for (int j = 0; j < 2; j++) {
            #pragma unroll
            for (int r = 0; r < 4; r++) {
                int brow = bt * 64 + wm * 32 + i * 16 + r0 + r;
                int dcol = nt * 64 + wn * 32 + j * 16 + c0;
                out[(size_t)brow * SD + (size_t)s * D_SZ + dcol] = acc[i][j][r];
            }
        }
    }
#undef K4_STAGE
#undef K4_COMPUTE
}

/* ------------------------------------------------------------------ */
extern "C" void kernel_launch(void* const* d_in, const int* in_sizes, int n_in,
                              void* d_out, int out_size, void* d_ws, size_t ws_size,
                              hipStream_t stream) {
    (void)in_sizes; (void)n_in; (void)out_size; (void)ws_size;

    const float* x  = (const float*)d_in[0];
    const float* gw = (const float*)d_in[1];
    const float* uw = (const float*)d_in[2];
    const float* dw = (const float*)d_in[3];
    const float* gc = (const float*)d_in[4];
    const float* uc = (const float*)d_in[5];
    const float* dc = (const float*)d_in[6];
    float* out = (float*)d_out;

    char* ws = (char*)d_ws;
    /* workspace layout (bytes):
       xs_bf16  [256][1024]        @ 0          (   524,288)
       bank     [256][65536] bf16  @ 524288     (33,554,432)
       hidden   [8][256][4096] bf16@ 34078720   (16,777,216)
       Wd       [8][1024][4096]bf16@ 50855936   (67,108,864) */
    unsigned short* xs   = (unsigned short*)(ws);
    unsigned short* bank = (unsigned short*)(ws + 524288);
    unsigned short* hid  = (unsigned short*)(ws + 34078720);
    unsigned short* wdp  = (unsigned short*)(ws + 50855936);

    k_cvt_x       <<<256,  256, 0, stream>>>(x, xs);
    k_bank_gemm   <<<1024, 512, 0, stream>>>(xs, gw, uw, bank);
    k_combine_silu<<<1024, 256, 0, stream>>>(bank, gc, uc, hid);
    k_wd_combine  <<<4096, 256, 0, stream>>>(dw, dc, wdp);
    k_down_gemm   <<<512,  256, 0, stream>>>(hid, wdp, out);
}